// Round 11
// baseline (4228.453 us; speedup 1.0000x reference)
//
#include <hip/hip_runtime.h>
#include <math.h>

#define F 128
#define HEADS 4
#define HD 32

// ---------------- CSR build ----------------
__global__ void hist_kernel(const int* __restrict__ tgt, int* __restrict__ cnt, int E) {
    int i = blockIdx.x * blockDim.x + threadIdx.x;
    if (i < E) atomicAdd(&cnt[tgt[i]], 1);
}

// 3-phase multi-block exclusive scan over cnt[N] -> row_off[N+1], next_[N].
// Phase 1: per-block (1024 elems) sums. Phase 2: one wave scans the block sums
// (CONTRACT: NB <= 64, i.e. N <= 65536; N = 50000 -> NB = 49) and writes
// row_off[N] = total. Phase 3: per-block local exclusive scan + block offset.
__global__ void scan_part1(const int* __restrict__ cnt, int* __restrict__ bsum, int N) {
    __shared__ int ws[4];
    int t = threadIdx.x;                 // 256
    int base = blockIdx.x * 1024;
    int s = 0;
#pragma unroll
    for (int r = 0; r < 4; r++) {
        int i = base + t + 256 * r;
        if (i < N) s += cnt[i];
    }
    for (int d = 1; d < 64; d <<= 1) s += __shfl_xor(s, d);
    if ((t & 63) == 0) ws[t >> 6] = s;
    __syncthreads();
    if (t == 0) bsum[blockIdx.x] = ws[0] + ws[1] + ws[2] + ws[3];
}

__global__ void scan_part2(const int* __restrict__ bsum, int* __restrict__ boff,
                           int* __restrict__ row_off, int NB, int N) {
    int t = threadIdx.x;                 // 64 threads (one wave), NB <= 64
    int v = (t < NB) ? bsum[t] : 0;
    int incl = v;
    for (int d = 1; d < 64; d <<= 1) {
        int n = __shfl_up(incl, d);
        if (t >= d) incl += n;
    }
    if (t < NB) boff[t] = incl - v;
    if (t == 63) row_off[N] = incl;      // grand total
}

__global__ void scan_part3(const int* __restrict__ cnt, const int* __restrict__ boff,
                           int* __restrict__ row_off, int* __restrict__ next_, int N) {
    __shared__ int wsum[4];
    int t = threadIdx.x, lane = t & 63, wid = t >> 6;
    int base = blockIdx.x * 1024;
    int i0 = base + t * 4;
    int e0 = (i0 + 0 < N) ? cnt[i0 + 0] : 0;
    int e1 = (i0 + 1 < N) ? cnt[i0 + 1] : 0;
    int e2 = (i0 + 2 < N) ? cnt[i0 + 2] : 0;
    int e3 = (i0 + 3 < N) ? cnt[i0 + 3] : 0;
    int p0 = e0, p1 = p0 + e1, p2 = p1 + e2, p3 = p2 + e3;   // inclusive within thread
    int incl = p3;
    for (int d = 1; d < 64; d <<= 1) {
        int n = __shfl_up(incl, d);
        if (lane >= d) incl += n;
    }
    int texcl = incl - p3;               // exclusive over threads within wave
    if (lane == 63) wsum[wid] = incl;
    __syncthreads();
    if (t == 0) {
        int a = wsum[0];
        int b = a + wsum[1];
        int c = b + wsum[2];
        wsum[1] = a; wsum[2] = b; wsum[3] = c; wsum[0] = 0;
    }
    __syncthreads();
    int off = boff[blockIdx.x] + wsum[wid] + texcl;
    if (i0 + 0 < N) { row_off[i0 + 0] = off;      next_[i0 + 0] = off; }
    if (i0 + 1 < N) { row_off[i0 + 1] = off + p0; next_[i0 + 1] = off + p0; }
    if (i0 + 2 < N) { row_off[i0 + 2] = off + p1; next_[i0 + 2] = off + p1; }
    if (i0 + 3 < N) { row_off[i0 + 3] = off + p2; next_[i0 + 3] = off + p2; }
}

__global__ void scatter_kernel(const int* __restrict__ src, const int* __restrict__ tgt,
                               int* __restrict__ next_, int* __restrict__ csr_src, int E) {
    int i = blockIdx.x * blockDim.x + threadIdx.x;
    if (i < E) {
        int tg = tgt[i];
        int pos = atomicAdd(&next_[tg], 1);
        csr_src[pos] = src[i];
    }
}

// ---------------- shared GEMM body: out[n][c] = sum_f x[n][f]*Wl[f][c] + b[c] ----------------
// Software-pipelined: register double-buffer, next 4-f step's W/X loads issue
// BEFORE current step's FMAs so ds_read latency hides under 64 FMAs/step.
// W reads: wave-uniform f, lanes spread 16B groups -> aggregate conflict-free.
// X reads: 2 distinct addrs/wave (broadcast pairs) -> free.
#define WLD(i, ff) (*(const float4*)&Wl[(ff + i) * F + 4 * c4])
#define XLD(j, ff) (*(const float4*)&Xl[(nl + 8 * j) * F + ff])
__device__ __forceinline__ void gemm_body(const float* __restrict__ x, const float* __restrict__ b,
                                          float* __restrict__ out, int N,
                                          const float* Wl, float* Xl) {
    int t = threadIdx.x;
    int c4 = t & 31;         // cols 4*c4 .. 4*c4+3
    int nl = t >> 5;         // 0..7 ; nodes nl, nl+8, nl+16, nl+24
    float4 bb = *(const float4*)&b[4 * c4];
    for (int nb = blockIdx.x * 32; nb < N; nb += gridDim.x * 32) {
        // stage 32 x-rows (1024 float4s, 4 per thread)
#pragma unroll
        for (int r = 0; r < 4; r++) {
            int idx = t + 256 * r;
            int node = idx >> 5, f4 = idx & 31;
            int gn = nb + node;
            float4 xv = (gn < N) ? *(const float4*)&x[(size_t)gn * F + 4 * f4]
                                 : make_float4(0.f, 0.f, 0.f, 0.f);
            *(float4*)&Xl[node * F + 4 * f4] = xv;
        }
        __syncthreads();
        float4 acc[4];
#pragma unroll
        for (int j = 0; j < 4; j++) acc[j] = bb;
        float4 cw0 = WLD(0, 0), cw1 = WLD(1, 0), cw2 = WLD(2, 0), cw3 = WLD(3, 0);
        float4 cx[4] = {XLD(0, 0), XLD(1, 0), XLD(2, 0), XLD(3, 0)};
#pragma unroll
        for (int f = 0; f < 128; f += 4) {
            float4 nw0, nw1, nw2, nw3, nx[4];
            if (f + 4 < 128) {
                nw0 = WLD(0, f + 4); nw1 = WLD(1, f + 4);
                nw2 = WLD(2, f + 4); nw3 = WLD(3, f + 4);
#pragma unroll
                for (int j = 0; j < 4; j++) nx[j] = XLD(j, f + 4);
            }
#pragma unroll
            for (int j = 0; j < 4; j++) {
                acc[j].x += cx[j].x * cw0.x + cx[j].y * cw1.x + cx[j].z * cw2.x + cx[j].w * cw3.x;
                acc[j].y += cx[j].x * cw0.y + cx[j].y * cw1.y + cx[j].z * cw2.y + cx[j].w * cw3.y;
                acc[j].z += cx[j].x * cw0.z + cx[j].y * cw1.z + cx[j].z * cw2.z + cx[j].w * cw3.z;
                acc[j].w += cx[j].x * cw0.w + cx[j].y * cw1.w + cx[j].z * cw2.w + cx[j].w * cw3.w;
            }
            if (f + 4 < 128) {
                cw0 = nw0; cw1 = nw1; cw2 = nw2; cw3 = nw3;
#pragma unroll
                for (int j = 0; j < 4; j++) cx[j] = nx[j];
            }
        }
#pragma unroll
        for (int j = 0; j < 4; j++) {
            int gn = nb + nl + 8 * j;
            if (gn < N) *(float4*)&out[(size_t)gn * F + 4 * c4] = acc[j];
        }
        __syncthreads();
    }
}

// QKV: weight layout w[h][f][d] -> column c = h*32+d. Staging: thread t owns
// dst col-group c4 = t&31 (h = c4>>3, d4 = c4&7) and rows f = (t>>5)+8r.
__global__ __launch_bounds__(256, 2) void qkv_kernel(
    const float* __restrict__ x,
    const float* __restrict__ wq, const float* __restrict__ bq,
    const float* __restrict__ wk, const float* __restrict__ bk,
    const float* __restrict__ wv, const float* __restrict__ bv,
    float* __restrict__ qo, float* __restrict__ ko, float* __restrict__ vo, int N) {
    __shared__ float Wl[128 * 128];
    __shared__ float Xl[32 * 128];
    const float* w = blockIdx.y == 0 ? wq : (blockIdx.y == 1 ? wk : wv);
    const float* b = blockIdx.y == 0 ? bq : (blockIdx.y == 1 ? bk : bv);
    float* out = blockIdx.y == 0 ? qo : (blockIdx.y == 1 ? ko : vo);
    int t = threadIdx.x;
    int c4 = t & 31, h = c4 >> 3, d4 = c4 & 7;
    const float4* w4 = (const float4*)w;
#pragma unroll
    for (int r = 0; r < 16; r++) {
        int f = (t >> 5) + 8 * r;
        float4 wv4 = w4[h * 1024 + f * 8 + d4];   // w[h][f][4*d4..+3]
        *(float4*)&Wl[f * F + 4 * c4] = wv4;
    }
    __syncthreads();
    gemm_body(x, b, out, N, Wl, Xl);
}

// Final: out = agg @ wo^T + bo ; wo layout [o][f].
__global__ __launch_bounds__(256, 2) void outproj_kernel(
    const float* __restrict__ aggin, const float* __restrict__ wo,
    const float* __restrict__ bo, float* __restrict__ out, int N) {
    __shared__ float Wl[128 * 128];
    __shared__ float Xl[32 * 128];
    int t = threadIdx.x;
    int c4 = t & 31;
#pragma unroll
    for (int r = 0; r < 16; r++) {
        int f = (t >> 5) + 8 * r;
        float4 wv4;
        wv4.x = wo[(size_t)(4 * c4 + 0) * F + f];
        wv4.y = wo[(size_t)(4 * c4 + 1) * F + f];
        wv4.z = wo[(size_t)(4 * c4 + 2) * F + f];
        wv4.w = wo[(size_t)(4 * c4 + 3) * F + f];
        *(float4*)&Wl[f * F + 4 * c4] = wv4;
    }
    __syncthreads();
    gemm_body(aggin, bo, out, N, Wl, Xl);
}

// ---------------- fused per-node edge attention ----------------
// One wave per target node; online softmax; writes normalized aggregate.
// Lane-mapping invariant: score lane = slot*4+h4 computes partial dots;
// xor-1/2 completes 32-dim dot; xor-4..32 reduces chunk stats over slots;
// agg lane owns dims {2*lane,2*lane+1}, head hagg = lane>>4; edge j's p for
// head hagg lives in lane (j<<2)|hagg, srcn in lane j<<2.
__global__ __launch_bounds__(256) void edge_attn_kernel(
    const float* __restrict__ q, const float* __restrict__ k, const float* __restrict__ v,
    const int* __restrict__ row_off, const int* __restrict__ csr_src,
    float* __restrict__ agg, int N) {
    int wave = (blockIdx.x * blockDim.x + threadIdx.x) >> 6;
    if (wave >= N) return;          // uniform per wave
    int lane = threadIdx.x & 63;
    int n = wave;
    int h4 = lane & 3;
    int slot = lane >> 2;
    int hagg = lane >> 4;

    float4 qf[8];
#pragma unroll
    for (int i = 0; i < 8; i++)
        qf[i] = *(const float4*)&q[(size_t)n * F + i * 16 + h4 * 4];

    int base = row_off[n];
    int deg = row_off[n + 1] - base;

    float m_sc = -INFINITY;
    float m_ag = -INFINITY;
    float den = 0.f;
    float2 accA = make_float2(0.f, 0.f);
    float2 accB = make_float2(0.f, 0.f);

    for (int c0 = 0; c0 < deg; c0 += 16) {
        int rem = deg - c0;
        int nj = rem < 16 ? rem : 16;
        int mye = c0 + slot;
        int srcn = (mye < deg) ? csr_src[base + mye] : 0;

        float sacc[4] = {0.f, 0.f, 0.f, 0.f};
#pragma unroll
        for (int i = 0; i < 8; i++) {
            float4 kk = *(const float4*)&k[(size_t)srcn * F + i * 16 + h4 * 4];
            sacc[i >> 1] += qf[i].x * kk.x + qf[i].y * kk.y + qf[i].z * kk.z + qf[i].w * kk.w;
        }
#pragma unroll
        for (int hh = 0; hh < 4; hh++) {
            sacc[hh] += __shfl_xor(sacc[hh], 1);
            sacc[hh] += __shfl_xor(sacc[hh], 2);
        }
        float s = h4 == 0 ? sacc[0] : h4 == 1 ? sacc[1] : h4 == 2 ? sacc[2] : sacc[3];
        if (mye >= deg) s = -INFINITY;

        float cm = s;
        cm = fmaxf(cm, __shfl_xor(cm, 4));
        cm = fmaxf(cm, __shfl_xor(cm, 8));
        cm = fmaxf(cm, __shfl_xor(cm, 16));
        cm = fmaxf(cm, __shfl_xor(cm, 32));

        float nm_sc = fmaxf(m_sc, cm);
        float cm_ag = __shfl(cm, hagg);
        float nm_ag = fmaxf(m_ag, cm_ag);

        float p = __expf(s - nm_sc);
        float psum = p;
        psum += __shfl_xor(psum, 4);
        psum += __shfl_xor(psum, 8);
        psum += __shfl_xor(psum, 16);
        psum += __shfl_xor(psum, 32);

        float scale = __expf(m_ag - nm_ag);
        den = den * scale + __shfl(psum, hagg);
        accA.x *= scale; accA.y *= scale;
        accB.x *= scale; accB.y *= scale;

#pragma unroll 4
        for (int j = 0; j < nj; j++) {
            float pj = __shfl(p, (j << 2) | hagg);
            int sj = __shfl(srcn, j << 2);
            float2 v2 = *(const float2*)&v[(size_t)sj * F + lane * 2];
            if (j & 1) { accB.x += pj * v2.x; accB.y += pj * v2.y; }
            else       { accA.x += pj * v2.x; accA.y += pj * v2.y; }
        }
        m_sc = nm_sc;
        m_ag = nm_ag;
    }
    float inv = (den > 0.f) ? 1.f / den : 0.f;
    *(float2*)&agg[(size_t)n * F + lane * 2] =
        make_float2((accA.x + accB.x) * inv, (accA.y + accB.y) * inv);
}

// ---------------- launch ----------------
extern "C" void kernel_launch(void* const* d_in, const int* in_sizes, int n_in,
                              void* d_out, int out_size, void* d_ws, size_t ws_size,
                              hipStream_t stream) {
    const float* x  = (const float*)d_in[0];
    const int*   ei = (const int*)d_in[1];
    const float* wq = (const float*)d_in[2];
    const float* bq = (const float*)d_in[3];
    const float* wk = (const float*)d_in[4];
    const float* bk = (const float*)d_in[5];
    const float* wv = (const float*)d_in[6];
    const float* bv = (const float*)d_in[7];
    const float* wo = (const float*)d_in[8];
    const float* bo = (const float*)d_in[9];
    float* out = (float*)d_out;

    int N = in_sizes[0] / F;
    int E = in_sizes[1] / 2;
    const int* srcs = ei;
    const int* tgts = ei + E;

    size_t need = (size_t)N * F * 4 * 4        // q, k, v, agg
                + (size_t)(N + 1) * 4          // row_off
                + (size_t)N * 4 * 2            // next_, cnt
                + (size_t)E * 4                // csr_src
                + 128 * 4;                     // bsum, boff
    if (ws_size < need) return;

    char* wsp = (char*)d_ws;
    float* q   = (float*)wsp; wsp += (size_t)N * F * 4;
    float* k   = (float*)wsp; wsp += (size_t)N * F * 4;
    float* v   = (float*)wsp; wsp += (size_t)N * F * 4;
    float* agg = (float*)wsp; wsp += (size_t)N * F * 4;
    int* row_off = (int*)wsp; wsp += (size_t)(N + 1) * 4;
    int* next_   = (int*)wsp; wsp += (size_t)N * 4;
    int* cnt     = (int*)wsp; wsp += (size_t)N * 4;
    int* csr_src = (int*)wsp; wsp += (size_t)E * 4;
    int* bsum    = (int*)wsp; wsp += 64 * 4;
    int* boff    = (int*)wsp; wsp += 64 * 4;

    int NB = (N + 1023) >> 10;   // 49 for N=50000; scan_part2 requires NB<=64

    hipMemsetAsync(cnt, 0, (size_t)N * 4, stream);
    hist_kernel<<<(E + 255) / 256, 256, 0, stream>>>(tgts, cnt, E);
    scan_part1<<<NB, 256, 0, stream>>>(cnt, bsum, N);
    scan_part2<<<1, 64, 0, stream>>>(bsum, boff, row_off, NB, N);
    scan_part3<<<NB, 256, 0, stream>>>(cnt, boff, row_off, next_, N);
    scatter_kernel<<<(E + 255) / 256, 256, 0, stream>>>(srcs, tgts, next_, csr_src, E);
    qkv_kernel<<<dim3(512, 3), 256, 0, stream>>>(x, wq, bq, wk, bk, wv, bv, q, k, v, N);
    edge_attn_kernel<<<(N + 3) / 4, 256, 0, stream>>>(q, k, v, row_off, csr_src, agg, N);
    outproj_kernel<<<512, 256, 0, stream>>>(agg, wo, bo, out, N);
}

// Round 12
// 479.094 us; speedup vs baseline: 8.8259x; 8.8259x over previous
//
#include <hip/hip_runtime.h>
#include <math.h>

#define F 128
#define HEADS 4
#define HD 32

// ---------------- CSR build ----------------
__global__ void hist_kernel(const int* __restrict__ tgt, int* __restrict__ cnt, int E) {
    int i = blockIdx.x * blockDim.x + threadIdx.x;
    if (i < E) atomicAdd(&cnt[tgt[i]], 1);
}

// 3-phase multi-block exclusive scan over cnt[N] -> row_off[N+1], next_[N].
// CONTRACT: NB <= 64 (N <= 65536); N = 50000 -> NB = 49.
__global__ void scan_part1(const int* __restrict__ cnt, int* __restrict__ bsum, int N) {
    __shared__ int ws[4];
    int t = threadIdx.x;                 // 256
    int base = blockIdx.x * 1024;
    int s = 0;
#pragma unroll
    for (int r = 0; r < 4; r++) {
        int i = base + t + 256 * r;
        if (i < N) s += cnt[i];
    }
    for (int d = 1; d < 64; d <<= 1) s += __shfl_xor(s, d);
    if ((t & 63) == 0) ws[t >> 6] = s;
    __syncthreads();
    if (t == 0) bsum[blockIdx.x] = ws[0] + ws[1] + ws[2] + ws[3];
}

__global__ void scan_part2(const int* __restrict__ bsum, int* __restrict__ boff,
                           int* __restrict__ row_off, int NB, int N) {
    int t = threadIdx.x;                 // 64 threads (one wave), NB <= 64
    int v = (t < NB) ? bsum[t] : 0;
    int incl = v;
    for (int d = 1; d < 64; d <<= 1) {
        int n = __shfl_up(incl, d);
        if (t >= d) incl += n;
    }
    if (t < NB) boff[t] = incl - v;
    if (t == 63) row_off[N] = incl;      // grand total
}

__global__ void scan_part3(const int* __restrict__ cnt, const int* __restrict__ boff,
                           int* __restrict__ row_off, int* __restrict__ next_, int N) {
    __shared__ int wsum[4];
    int t = threadIdx.x, lane = t & 63, wid = t >> 6;
    int base = blockIdx.x * 1024;
    int i0 = base + t * 4;
    int e0 = (i0 + 0 < N) ? cnt[i0 + 0] : 0;
    int e1 = (i0 + 1 < N) ? cnt[i0 + 1] : 0;
    int e2 = (i0 + 2 < N) ? cnt[i0 + 2] : 0;
    int e3 = (i0 + 3 < N) ? cnt[i0 + 3] : 0;
    int p0 = e0, p1 = p0 + e1, p2 = p1 + e2, p3 = p2 + e3;   // inclusive within thread
    int incl = p3;
    for (int d = 1; d < 64; d <<= 1) {
        int n = __shfl_up(incl, d);
        if (lane >= d) incl += n;
    }
    int texcl = incl - p3;               // exclusive over threads within wave
    if (lane == 63) wsum[wid] = incl;
    __syncthreads();
    if (t == 0) {
        int a = wsum[0];
        int b = a + wsum[1];
        int c = b + wsum[2];
        wsum[1] = a; wsum[2] = b; wsum[3] = c; wsum[0] = 0;
    }
    __syncthreads();
    int off = boff[blockIdx.x] + wsum[wid] + texcl;
    if (i0 + 0 < N) { row_off[i0 + 0] = off;      next_[i0 + 0] = off; }
    if (i0 + 1 < N) { row_off[i0 + 1] = off + p0; next_[i0 + 1] = off + p0; }
    if (i0 + 2 < N) { row_off[i0 + 2] = off + p1; next_[i0 + 2] = off + p1; }
    if (i0 + 3 < N) { row_off[i0 + 3] = off + p2; next_[i0 + 3] = off + p2; }
}

__global__ void scatter_kernel(const int* __restrict__ src, const int* __restrict__ tgt,
                               int* __restrict__ next_, int* __restrict__ csr_src, int E) {
    int i = blockIdx.x * blockDim.x + threadIdx.x;
    if (i < E) {
        int tg = tgt[i];
        int pos = atomicAdd(&next_[tg], 1);
        csr_src[pos] = src[i];
    }
}

// ---------------- shared GEMM body: out[n][c] = sum_f x[n][f]*Wl[f][c] + b[c] ----------------
// REVERTED to the R6-measured version (135 us, VALUBusy 70%, 0 spill).
// R8's manual register double-buffer spilled to scratch (9.3 GB VMEM traffic,
// VALUBusy 1.7%) — do NOT reintroduce manual SW-pipelining here (rule #20).
// W reads: wave-uniform f, lanes spread 16B groups -> aggregate conflict-free.
// X reads: 2 distinct addrs/wave (broadcast pairs) -> free (m136).
__device__ __forceinline__ void gemm_body(const float* __restrict__ x, const float* __restrict__ b,
                                          float* __restrict__ out, int N,
                                          const float* Wl, float* Xl) {
    int t = threadIdx.x;
    int c4 = t & 31;         // cols 4*c4 .. 4*c4+3
    int nl = t >> 5;         // 0..7 ; nodes nl, nl+8, nl+16, nl+24
    float4 bb = *(const float4*)&b[4 * c4];
    for (int nb = blockIdx.x * 32; nb < N; nb += gridDim.x * 32) {
        // stage 32 x-rows (float4 granularity; 1024 float4s, 4 per thread)
#pragma unroll
        for (int r = 0; r < 4; r++) {
            int idx = t + 256 * r;
            int node = idx >> 5, f4 = idx & 31;
            int gn = nb + node;
            float4 xv = (gn < N) ? *(const float4*)&x[(size_t)gn * F + 4 * f4]
                                 : make_float4(0.f, 0.f, 0.f, 0.f);
            *(float4*)&Xl[node * F + 4 * f4] = xv;
        }
        __syncthreads();
        float4 acc[4];
#pragma unroll
        for (int j = 0; j < 4; j++) acc[j] = bb;
#pragma unroll 2
        for (int f = 0; f < 128; f += 4) {
            float4 w0 = *(const float4*)&Wl[(f + 0) * F + 4 * c4];
            float4 w1 = *(const float4*)&Wl[(f + 1) * F + 4 * c4];
            float4 w2 = *(const float4*)&Wl[(f + 2) * F + 4 * c4];
            float4 w3 = *(const float4*)&Wl[(f + 3) * F + 4 * c4];
#pragma unroll
            for (int j = 0; j < 4; j++) {
                float4 xv = *(const float4*)&Xl[(nl + 8 * j) * F + f];
                acc[j].x += xv.x * w0.x + xv.y * w1.x + xv.z * w2.x + xv.w * w3.x;
                acc[j].y += xv.x * w0.y + xv.y * w1.y + xv.z * w2.y + xv.w * w3.y;
                acc[j].z += xv.x * w0.z + xv.y * w1.z + xv.z * w2.z + xv.w * w3.z;
                acc[j].w += xv.x * w0.w + xv.y * w1.w + xv.z * w2.w + xv.w * w3.w;
            }
        }
#pragma unroll
        for (int j = 0; j < 4; j++) {
            int gn = nb + nl + 8 * j;
            if (gn < N) *(float4*)&out[(size_t)gn * F + 4 * c4] = acc[j];
        }
        __syncthreads();
    }
}

// QKV: weight layout w[h][f][d] -> column c = h*32+d. Staging: thread t owns
// dst col-group c4 = t&31 (h = c4>>3, d4 = c4&7) and rows f = (t>>5)+8r.
__global__ __launch_bounds__(256, 2) void qkv_kernel(
    const float* __restrict__ x,
    const float* __restrict__ wq, const float* __restrict__ bq,
    const float* __restrict__ wk, const float* __restrict__ bk,
    const float* __restrict__ wv, const float* __restrict__ bv,
    float* __restrict__ qo, float* __restrict__ ko, float* __restrict__ vo, int N) {
    __shared__ float Wl[128 * 128];
    __shared__ float Xl[32 * 128];
    const float* w = blockIdx.y == 0 ? wq : (blockIdx.y == 1 ? wk : wv);
    const float* b = blockIdx.y == 0 ? bq : (blockIdx.y == 1 ? bk : bv);
    float* out = blockIdx.y == 0 ? qo : (blockIdx.y == 1 ? ko : vo);
    int t = threadIdx.x;
    int c4 = t & 31, h = c4 >> 3, d4 = c4 & 7;
    const float4* w4 = (const float4*)w;
#pragma unroll
    for (int r = 0; r < 16; r++) {
        int f = (t >> 5) + 8 * r;
        float4 wv4 = w4[h * 1024 + f * 8 + d4];   // w[h][f][4*d4..+3]
        *(float4*)&Wl[f * F + 4 * c4] = wv4;
    }
    __syncthreads();
    gemm_body(x, b, out, N, Wl, Xl);
}

// Final: out = agg @ wo^T + bo ; wo layout [o][f]. Transpose during staging via
// strided global gather (wo is L2-resident).
__global__ __launch_bounds__(256, 2) void outproj_kernel(
    const float* __restrict__ aggin, const float* __restrict__ wo,
    const float* __restrict__ bo, float* __restrict__ out, int N) {
    __shared__ float Wl[128 * 128];
    __shared__ float Xl[32 * 128];
    int t = threadIdx.x;
    int c4 = t & 31;
#pragma unroll
    for (int r = 0; r < 16; r++) {
        int f = (t >> 5) + 8 * r;
        float4 wv4;
        wv4.x = wo[(size_t)(4 * c4 + 0) * F + f];
        wv4.y = wo[(size_t)(4 * c4 + 1) * F + f];
        wv4.z = wo[(size_t)(4 * c4 + 2) * F + f];
        wv4.w = wo[(size_t)(4 * c4 + 3) * F + f];
        *(float4*)&Wl[f * F + 4 * c4] = wv4;
    }
    __syncthreads();
    gemm_body(aggin, bo, out, N, Wl, Xl);
}

// ---------------- fused per-node edge attention ----------------
// One wave per target node; online softmax; writes normalized aggregate.
// Lane-mapping invariant: score lane = slot*4+h4 computes partial dots;
// xor-1/2 completes 32-dim dot; xor-4..32 reduces chunk stats over slots;
// agg lane owns dims {2*lane,2*lane+1}, head hagg = lane>>4; edge j's p for
// head hagg lives in lane (j<<2)|hagg, srcn in lane j<<2.
__global__ __launch_bounds__(256) void edge_attn_kernel(
    const float* __restrict__ q, const float* __restrict__ k, const float* __restrict__ v,
    const int* __restrict__ row_off, const int* __restrict__ csr_src,
    float* __restrict__ agg, int N) {
    int wave = (blockIdx.x * blockDim.x + threadIdx.x) >> 6;
    if (wave >= N) return;          // uniform per wave
    int lane = threadIdx.x & 63;
    int n = wave;
    int h4 = lane & 3;
    int slot = lane >> 2;
    int hagg = lane >> 4;

    float4 qf[8];
#pragma unroll
    for (int i = 0; i < 8; i++)
        qf[i] = *(const float4*)&q[(size_t)n * F + i * 16 + h4 * 4];

    int base = row_off[n];
    int deg = row_off[n + 1] - base;

    float m_sc = -INFINITY;
    float m_ag = -INFINITY;
    float den = 0.f;
    float2 accA = make_float2(0.f, 0.f);
    float2 accB = make_float2(0.f, 0.f);

    for (int c0 = 0; c0 < deg; c0 += 16) {
        int rem = deg - c0;
        int nj = rem < 16 ? rem : 16;
        int mye = c0 + slot;
        int srcn = (mye < deg) ? csr_src[base + mye] : 0;

        float sacc[4] = {0.f, 0.f, 0.f, 0.f};
#pragma unroll
        for (int i = 0; i < 8; i++) {
            float4 kk = *(const float4*)&k[(size_t)srcn * F + i * 16 + h4 * 4];
            sacc[i >> 1] += qf[i].x * kk.x + qf[i].y * kk.y + qf[i].z * kk.z + qf[i].w * kk.w;
        }
#pragma unroll
        for (int hh = 0; hh < 4; hh++) {
            sacc[hh] += __shfl_xor(sacc[hh], 1);
            sacc[hh] += __shfl_xor(sacc[hh], 2);
        }
        float s = h4 == 0 ? sacc[0] : h4 == 1 ? sacc[1] : h4 == 2 ? sacc[2] : sacc[3];
        if (mye >= deg) s = -INFINITY;

        float cm = s;
        cm = fmaxf(cm, __shfl_xor(cm, 4));
        cm = fmaxf(cm, __shfl_xor(cm, 8));
        cm = fmaxf(cm, __shfl_xor(cm, 16));
        cm = fmaxf(cm, __shfl_xor(cm, 32));

        float nm_sc = fmaxf(m_sc, cm);
        float cm_ag = __shfl(cm, hagg);
        float nm_ag = fmaxf(m_ag, cm_ag);

        float p = __expf(s - nm_sc);
        float psum = p;
        psum += __shfl_xor(psum, 4);
        psum += __shfl_xor(psum, 8);
        psum += __shfl_xor(psum, 16);
        psum += __shfl_xor(psum, 32);

        float scale = __expf(m_ag - nm_ag);
        den = den * scale + __shfl(psum, hagg);
        accA.x *= scale; accA.y *= scale;
        accB.x *= scale; accB.y *= scale;

#pragma unroll 4
        for (int j = 0; j < nj; j++) {
            float pj = __shfl(p, (j << 2) | hagg);
            int sj = __shfl(srcn, j << 2);
            float2 v2 = *(const float2*)&v[(size_t)sj * F + lane * 2];
            if (j & 1) { accB.x += pj * v2.x; accB.y += pj * v2.y; }
            else       { accA.x += pj * v2.x; accA.y += pj * v2.y; }
        }
        m_sc = nm_sc;
        m_ag = nm_ag;
    }
    float inv = (den > 0.f) ? 1.f / den : 0.f;
    *(float2*)&agg[(size_t)n * F + lane * 2] =
        make_float2((accA.x + accB.x) * inv, (accA.y + accB.y) * inv);
}

// ---------------- launch ----------------
extern "C" void kernel_launch(void* const* d_in, const int* in_sizes, int n_in,
                              void* d_out, int out_size, void* d_ws, size_t ws_size,
                              hipStream_t stream) {
    const float* x  = (const float*)d_in[0];
    const int*   ei = (const int*)d_in[1];
    const float* wq = (const float*)d_in[2];
    const float* bq = (const float*)d_in[3];
    const float* wk = (const float*)d_in[4];
    const float* bk = (const float*)d_in[5];
    const float* wv = (const float*)d_in[6];
    const float* bv = (const float*)d_in[7];
    const float* wo = (const float*)d_in[8];
    const float* bo = (const float*)d_in[9];
    float* out = (float*)d_out;

    int N = in_sizes[0] / F;
    int E = in_sizes[1] / 2;
    const int* srcs = ei;
    const int* tgts = ei + E;

    size_t need = (size_t)N * F * 4 * 4        // q, k, v, agg
                + (size_t)(N + 1) * 4          // row_off
                + (size_t)N * 4 * 2            // next_, cnt
                + (size_t)E * 4                // csr_src
                + 128 * 4;                     // bsum, boff
    if (ws_size < need) return;

    char* wsp = (char*)d_ws;
    float* q   = (float*)wsp; wsp += (size_t)N * F * 4;
    float* k   = (float*)wsp; wsp += (size_t)N * F * 4;
    float* v   = (float*)wsp; wsp += (size_t)N * F * 4;
    float* agg = (float*)wsp; wsp += (size_t)N * F * 4;
    int* row_off = (int*)wsp; wsp += (size_t)(N + 1) * 4;
    int* next_   = (int*)wsp; wsp += (size_t)N * 4;
    int* cnt     = (int*)wsp; wsp += (size_t)N * 4;
    int* csr_src = (int*)wsp; wsp += (size_t)E * 4;
    int* bsum    = (int*)wsp; wsp += 64 * 4;
    int* boff    = (int*)wsp; wsp += 64 * 4;

    int NB = (N + 1023) >> 10;   // 49 for N=50000; scan_part2 requires NB<=64

    hipMemsetAsync(cnt, 0, (size_t)N * 4, stream);
    hist_kernel<<<(E + 255) / 256, 256, 0, stream>>>(tgts, cnt, E);
    scan_part1<<<NB, 256, 0, stream>>>(cnt, bsum, N);
    scan_part2<<<1, 64, 0, stream>>>(bsum, boff, row_off, NB, N);
    scan_part3<<<NB, 256, 0, stream>>>(cnt, boff, row_off, next_, N);
    scatter_kernel<<<(E + 255) / 256, 256, 0, stream>>>(srcs, tgts, next_, csr_src, E);
    qkv_kernel<<<dim3(512, 3), 256, 0, stream>>>(x, wq, bq, wk, bk, wv, bv, q, k, v, N);
    edge_attn_kernel<<<(N + 3) / 4, 256, 0, stream>>>(q, k, v, row_off, csr_src, agg, N);
    outproj_kernel<<<512, 256, 0, stream>>>(agg, wo, bo, out, N);
}

// Round 14
// 418.402 us; speedup vs baseline: 10.1062x; 1.1451x over previous
//
#include <hip/hip_runtime.h>
#include <math.h>

#define F 128
#define HEADS 4
#define HD 32

typedef unsigned short ushort_t;
typedef unsigned int uint_t;

// bf16 helpers (RNE pack, shift unpack)
__device__ __forceinline__ ushort_t f2bf(float f) {
    uint_t u = __float_as_uint(f);
    u += 0x7FFFu + ((u >> 16) & 1u);
    return (ushort_t)(u >> 16);
}
__device__ __forceinline__ float bf2f(ushort_t h) {
    return __uint_as_float(((uint_t)h) << 16);
}

// ---------------- CSR build ----------------
__global__ void hist_kernel(const int* __restrict__ tgt, int* __restrict__ cnt, int E) {
    int i = blockIdx.x * blockDim.x + threadIdx.x;
    if (i < E) atomicAdd(&cnt[tgt[i]], 1);
}

// 3-phase multi-block exclusive scan. CONTRACT: NB <= 64 (N <= 65536).
__global__ void scan_part1(const int* __restrict__ cnt, int* __restrict__ bsum, int N) {
    __shared__ int ws[4];
    int t = threadIdx.x;                 // 256
    int base = blockIdx.x * 1024;
    int s = 0;
#pragma unroll
    for (int r = 0; r < 4; r++) {
        int i = base + t + 256 * r;
        if (i < N) s += cnt[i];
    }
    for (int d = 1; d < 64; d <<= 1) s += __shfl_xor(s, d);
    if ((t & 63) == 0) ws[t >> 6] = s;
    __syncthreads();
    if (t == 0) bsum[blockIdx.x] = ws[0] + ws[1] + ws[2] + ws[3];
}

__global__ void scan_part2(const int* __restrict__ bsum, int* __restrict__ boff,
                           int* __restrict__ row_off, int NB, int N) {
    int t = threadIdx.x;                 // 64 threads (one wave), NB <= 64
    int v = (t < NB) ? bsum[t] : 0;
    int incl = v;
    for (int d = 1; d < 64; d <<= 1) {
        int n = __shfl_up(incl, d);
        if (t >= d) incl += n;
    }
    if (t < NB) boff[t] = incl - v;
    if (t == 63) row_off[N] = incl;      // grand total
}

__global__ void scan_part3(const int* __restrict__ cnt, const int* __restrict__ boff,
                           int* __restrict__ row_off, int* __restrict__ next_, int N) {
    __shared__ int wsum[4];
    int t = threadIdx.x, lane = t & 63, wid = t >> 6;
    int base = blockIdx.x * 1024;
    int i0 = base + t * 4;
    int e0 = (i0 + 0 < N) ? cnt[i0 + 0] : 0;
    int e1 = (i0 + 1 < N) ? cnt[i0 + 1] : 0;
    int e2 = (i0 + 2 < N) ? cnt[i0 + 2] : 0;
    int e3 = (i0 + 3 < N) ? cnt[i0 + 3] : 0;
    int p0 = e0, p1 = p0 + e1, p2 = p1 + e2, p3 = p2 + e3;
    int incl = p3;
    for (int d = 1; d < 64; d <<= 1) {
        int n = __shfl_up(incl, d);
        if (lane >= d) incl += n;
    }
    int texcl = incl - p3;
    if (lane == 63) wsum[wid] = incl;
    __syncthreads();
    if (t == 0) {
        int a = wsum[0];
        int b = a + wsum[1];
        int c = b + wsum[2];
        wsum[1] = a; wsum[2] = b; wsum[3] = c; wsum[0] = 0;
    }
    __syncthreads();
    int off = boff[blockIdx.x] + wsum[wid] + texcl;
    if (i0 + 0 < N) { row_off[i0 + 0] = off;      next_[i0 + 0] = off; }
    if (i0 + 1 < N) { row_off[i0 + 1] = off + p0; next_[i0 + 1] = off + p0; }
    if (i0 + 2 < N) { row_off[i0 + 2] = off + p1; next_[i0 + 2] = off + p1; }
    if (i0 + 3 < N) { row_off[i0 + 3] = off + p2; next_[i0 + 3] = off + p2; }
}

__global__ void scatter_kernel(const int* __restrict__ src, const int* __restrict__ tgt,
                               int* __restrict__ next_, int* __restrict__ csr_src, int E) {
    int i = blockIdx.x * blockDim.x + threadIdx.x;
    if (i < E) {
        int tg = tgt[i];
        int pos = atomicAdd(&next_[tg], 1);
        csr_src[pos] = src[i];
    }
}

// ---------------- shared GEMM body (R6-measured: 73 TF, VALUBusy 70%) ----------------
// Do NOT reintroduce manual SW-pipelining (R8/R11: register spill, 9.3 GB scratch).
// Output store overloads: fp32 row (float4) or bf16 row (ushort4).
__device__ __forceinline__ void store4(float* p, float4 v) { *(float4*)p = v; }
__device__ __forceinline__ void store4(ushort_t* p, float4 v) {
    ushort4 h;
    h.x = f2bf(v.x); h.y = f2bf(v.y); h.z = f2bf(v.z); h.w = f2bf(v.w);
    *(ushort4*)p = h;
}

template<typename OT>
__device__ __forceinline__ void gemm_body(const float* __restrict__ x, const float* __restrict__ b,
                                          OT* __restrict__ out, int N,
                                          const float* Wl, float* Xl) {
    int t = threadIdx.x;
    int c4 = t & 31;         // cols 4*c4 .. 4*c4+3
    int nl = t >> 5;         // 0..7 ; nodes nl, nl+8, nl+16, nl+24
    float4 bb = *(const float4*)&b[4 * c4];
    for (int nb = blockIdx.x * 32; nb < N; nb += gridDim.x * 32) {
#pragma unroll
        for (int r = 0; r < 4; r++) {
            int idx = t + 256 * r;
            int node = idx >> 5, f4 = idx & 31;
            int gn = nb + node;
            float4 xv = (gn < N) ? *(const float4*)&x[(size_t)gn * F + 4 * f4]
                                 : make_float4(0.f, 0.f, 0.f, 0.f);
            *(float4*)&Xl[node * F + 4 * f4] = xv;
        }
        __syncthreads();
        float4 acc[4];
#pragma unroll
        for (int j = 0; j < 4; j++) acc[j] = bb;
#pragma unroll 2
        for (int f = 0; f < 128; f += 4) {
            float4 w0 = *(const float4*)&Wl[(f + 0) * F + 4 * c4];
            float4 w1 = *(const float4*)&Wl[(f + 1) * F + 4 * c4];
            float4 w2 = *(const float4*)&Wl[(f + 2) * F + 4 * c4];
            float4 w3 = *(const float4*)&Wl[(f + 3) * F + 4 * c4];
#pragma unroll
            for (int j = 0; j < 4; j++) {
                float4 xv = *(const float4*)&Xl[(nl + 8 * j) * F + f];
                acc[j].x += xv.x * w0.x + xv.y * w1.x + xv.z * w2.x + xv.w * w3.x;
                acc[j].y += xv.x * w0.y + xv.y * w1.y + xv.z * w2.y + xv.w * w3.y;
                acc[j].z += xv.x * w0.z + xv.y * w1.z + xv.z * w2.z + xv.w * w3.z;
                acc[j].w += xv.x * w0.w + xv.y * w1.w + xv.z * w2.w + xv.w * w3.w;
            }
        }
#pragma unroll
        for (int j = 0; j < 4; j++) {
            int gn = nb + nl + 8 * j;
            if (gn < N) store4(&out[(size_t)gn * F + 4 * c4], acc[j]);
        }
        __syncthreads();
    }
}

// Q projection (fp32 out). Weight layout w[h][f][d] -> column c = h*32+d.
__global__ __launch_bounds__(256, 2) void proj_q_kernel(
    const float* __restrict__ x, const float* __restrict__ wq, const float* __restrict__ bq,
    float* __restrict__ qo, int N) {
    __shared__ float Wl[128 * 128];
    __shared__ float Xl[32 * 128];
    int t = threadIdx.x;
    int c4 = t & 31, h = c4 >> 3, d4 = c4 & 7;
    const float4* w4 = (const float4*)wq;
#pragma unroll
    for (int r = 0; r < 16; r++) {
        int f = (t >> 5) + 8 * r;
        *(float4*)&Wl[f * F + 4 * c4] = w4[h * 1024 + f * 8 + d4];
    }
    __syncthreads();
    gemm_body<float>(x, bq, qo, N, Wl, Xl);
}

// K/V projections (bf16 out). blockIdx.y: 0 -> k, 1 -> v.
__global__ __launch_bounds__(256, 2) void proj_kv_kernel(
    const float* __restrict__ x,
    const float* __restrict__ wk, const float* __restrict__ bk,
    const float* __restrict__ wv, const float* __restrict__ bv,
    ushort_t* __restrict__ ko, ushort_t* __restrict__ vo, int N) {
    __shared__ float Wl[128 * 128];
    __shared__ float Xl[32 * 128];
    const float* w = blockIdx.y == 0 ? wk : wv;
    const float* b = blockIdx.y == 0 ? bk : bv;
    ushort_t* out = blockIdx.y == 0 ? ko : vo;
    int t = threadIdx.x;
    int c4 = t & 31, h = c4 >> 3, d4 = c4 & 7;
    const float4* w4 = (const float4*)w;
#pragma unroll
    for (int r = 0; r < 16; r++) {
        int f = (t >> 5) + 8 * r;
        *(float4*)&Wl[f * F + 4 * c4] = w4[h * 1024 + f * 8 + d4];
    }
    __syncthreads();
    gemm_body<ushort_t>(x, b, out, N, Wl, Xl);
}

// Final: out = agg @ wo^T + bo ; wo layout [o][f] (transpose gather, L2-resident).
__global__ __launch_bounds__(256, 2) void outproj_kernel(
    const float* __restrict__ aggin, const float* __restrict__ wo,
    const float* __restrict__ bo, float* __restrict__ out, int N) {
    __shared__ float Wl[128 * 128];
    __shared__ float Xl[32 * 128];
    int t = threadIdx.x;
    int c4 = t & 31;
#pragma unroll
    for (int r = 0; r < 16; r++) {
        int f = (t >> 5) + 8 * r;
        float4 wv4;
        wv4.x = wo[(size_t)(4 * c4 + 0) * F + f];
        wv4.y = wo[(size_t)(4 * c4 + 1) * F + f];
        wv4.z = wo[(size_t)(4 * c4 + 2) * F + f];
        wv4.w = wo[(size_t)(4 * c4 + 3) * F + f];
        *(float4*)&Wl[f * F + 4 * c4] = wv4;
    }
    __syncthreads();
    gemm_body<float>(aggin, bo, out, N, Wl, Xl);
}

// ---------------- fused per-node edge attention (bf16 k/v) ----------------
// One wave per target node; online softmax; writes normalized fp32 aggregate.
// Lane-mapping invariant: score lane = slot*4+h4 computes partial dots;
// xor-1/2 completes 32-dim dot; xor-4..32 reduces chunk stats over slots;
// agg lane owns dims {2*lane,2*lane+1}, head hagg = lane>>4; edge j's p for
// head hagg lives in lane (j<<2)|hagg, srcn in lane j<<2.
__global__ __launch_bounds__(256) void edge_attn_kernel(
    const float* __restrict__ q, const ushort_t* __restrict__ kb,
    const ushort_t* __restrict__ vb,
    const int* __restrict__ row_off, const int* __restrict__ csr_src,
    float* __restrict__ agg, int N) {
    int wave = (blockIdx.x * blockDim.x + threadIdx.x) >> 6;
    if (wave >= N) return;          // uniform per wave
    int lane = threadIdx.x & 63;
    int n = wave;
    int h4 = lane & 3;
    int slot = lane >> 2;
    int hagg = lane >> 4;

    float4 qf[8];
#pragma unroll
    for (int i = 0; i < 8; i++)
        qf[i] = *(const float4*)&q[(size_t)n * F + i * 16 + h4 * 4];

    int base = row_off[n];
    int deg = row_off[n + 1] - base;

    float m_sc = -INFINITY;
    float m_ag = -INFINITY;
    float den = 0.f;
    float2 accA = make_float2(0.f, 0.f);
    float2 accB = make_float2(0.f, 0.f);

    for (int c0 = 0; c0 < deg; c0 += 16) {
        int rem = deg - c0;
        int nj = rem < 16 ? rem : 16;
        int mye = c0 + slot;
        int srcn = (mye < deg) ? csr_src[base + mye] : 0;

        float sacc[4] = {0.f, 0.f, 0.f, 0.f};
#pragma unroll
        for (int i = 0; i < 8; i++) {
            ushort4 kk = *(const ushort4*)&kb[(size_t)srcn * F + i * 16 + h4 * 4];
            sacc[i >> 1] += qf[i].x * bf2f(kk.x) + qf[i].y * bf2f(kk.y)
                          + qf[i].z * bf2f(kk.z) + qf[i].w * bf2f(kk.w);
        }
#pragma unroll
        for (int hh = 0; hh < 4; hh++) {
            sacc[hh] += __shfl_xor(sacc[hh], 1);
            sacc[hh] += __shfl_xor(sacc[hh], 2);
        }
        float s = h4 == 0 ? sacc[0] : h4 == 1 ? sacc[1] : h4 == 2 ? sacc[2] : sacc[3];
        if (mye >= deg) s = -INFINITY;

        float cm = s;
        cm = fmaxf(cm, __shfl_xor(cm, 4));
        cm = fmaxf(cm, __shfl_xor(cm, 8));
        cm = fmaxf(cm, __shfl_xor(cm, 16));
        cm = fmaxf(cm, __shfl_xor(cm, 32));

        float nm_sc = fmaxf(m_sc, cm);
        float cm_ag = __shfl(cm, hagg);
        float nm_ag = fmaxf(m_ag, cm_ag);

        float p = __expf(s - nm_sc);
        float psum = p;
        psum += __shfl_xor(psum, 4);
        psum += __shfl_xor(psum, 8);
        psum += __shfl_xor(psum, 16);
        psum += __shfl_xor(psum, 32);

        float scale = __expf(m_ag - nm_ag);
        den = den * scale + __shfl(psum, hagg);
        accA.x *= scale; accA.y *= scale;
        accB.x *= scale; accB.y *= scale;

#pragma unroll 4
        for (int j = 0; j < nj; j++) {
            float pj = __shfl(p, (j << 2) | hagg);
            int sj = __shfl(srcn, j << 2);
            uint_t vv = *(const uint_t*)&vb[(size_t)sj * F + lane * 2];
            float v0 = bf2f((ushort_t)(vv & 0xFFFFu));
            float v1 = bf2f((ushort_t)(vv >> 16));
            if (j & 1) { accB.x += pj * v0; accB.y += pj * v1; }
            else       { accA.x += pj * v0; accA.y += pj * v1; }
        }
        m_sc = nm_sc;
        m_ag = nm_ag;
    }
    float inv = (den > 0.f) ? 1.f / den : 0.f;
    *(float2*)&agg[(size_t)n * F + lane * 2] =
        make_float2((accA.x + accB.x) * inv, (accA.y + accB.y) * inv);
}

// ---------------- launch ----------------
extern "C" void kernel_launch(void* const* d_in, const int* in_sizes, int n_in,
                              void* d_out, int out_size, void* d_ws, size_t ws_size,
                              hipStream_t stream) {
    const float* x  = (const float*)d_in[0];
    const int*   ei = (const int*)d_in[1];
    const float* wq = (const float*)d_in[2];
    const float* bq = (const float*)d_in[3];
    const float* wk = (const float*)d_in[4];
    const float* bk = (const float*)d_in[5];
    const float* wv = (const float*)d_in[6];
    const float* bv = (const float*)d_in[7];
    const float* wo = (const float*)d_in[8];
    const float* bo = (const float*)d_in[9];
    float* out = (float*)d_out;

    int N = in_sizes[0] / F;
    int E = in_sizes[1] / 2;
    const int* srcs = ei;
    const int* tgts = ei + E;

    size_t need = (size_t)N * F * 4 * 2        // q, agg (fp32)
                + (size_t)N * F * 2 * 2        // k, v (bf16)
                + (size_t)(N + 1) * 4          // row_off
                + (size_t)N * 4 * 2            // next_, cnt
                + (size_t)E * 4                // csr_src
                + 128 * 4;                     // bsum, boff
    if (ws_size < need) return;

    char* wsp = (char*)d_ws;
    float* q       = (float*)wsp;    wsp += (size_t)N * F * 4;
    float* agg     = (float*)wsp;    wsp += (size_t)N * F * 4;
    ushort_t* kb   = (ushort_t*)wsp; wsp += (size_t)N * F * 2;
    ushort_t* vb   = (ushort_t*)wsp; wsp += (size_t)N * F * 2;
    int* row_off = (int*)wsp; wsp += (size_t)(N + 1) * 4;
    int* next_   = (int*)wsp; wsp += (size_t)N * 4;
    int* cnt     = (int*)wsp; wsp += (size_t)N * 4;
    int* csr_src = (int*)wsp; wsp += (size_t)E * 4;
    int* bsum    = (int*)wsp; wsp += 64 * 4;
    int* boff    = (int*)wsp; wsp += 64 * 4;

    int NB = (N + 1023) >> 10;   // 49 for N=50000; scan_part2 requires NB<=64

    hipMemsetAsync(cnt, 0, (size_t)N * 4, stream);
    hist_kernel<<<(E + 255) / 256, 256, 0, stream>>>(tgts, cnt, E);
    scan_part1<<<NB, 256, 0, stream>>>(cnt, bsum, N);
    scan_part2<<<1, 64, 0, stream>>>(bsum, boff, row_off, NB, N);
    scan_part3<<<NB, 256, 0, stream>>>(cnt, boff, row_off, next_, N);
    scatter_kernel<<<(E + 255) / 256, 256, 0, stream>>>(srcs, tgts, next_, csr_src, E);
    proj_q_kernel<<<512, 256, 0, stream>>>(x, wq, bq, q, N);
    proj_kv_kernel<<<dim3(512, 2), 256, 0, stream>>>(x, wk, bk, wv, bv, kb, vb, N);
    edge_attn_kernel<<<(N + 3) / 4, 256, 0, stream>>>(q, kb, vb, row_off, csr_src, agg, N);
    outproj_kernel<<<512, 256, 0, stream>>>(agg, wo, bo, out, N);
}

// Round 16
// 377.935 us; speedup vs baseline: 11.1883x; 1.1071x over previous
//
#include <hip/hip_runtime.h>
#include <math.h>

#define F 128
#define HEADS 4
#define HD 32

typedef unsigned short ushort_t;
typedef unsigned int uint_t;

// bf16 helpers (RNE pack, shift unpack)
__device__ __forceinline__ ushort_t f2bf(float f) {
    uint_t u = __float_as_uint(f);
    u += 0x7FFFu + ((u >> 16) & 1u);
    return (ushort_t)(u >> 16);
}
__device__ __forceinline__ float bf2f(ushort_t h) {
    return __uint_as_float(((uint_t)h) << 16);
}

// ---------------- CSR build ----------------
__global__ void hist_kernel(const int* __restrict__ tgt, int* __restrict__ cnt, int E) {
    int i = blockIdx.x * blockDim.x + threadIdx.x;
    if (i < E) atomicAdd(&cnt[tgt[i]], 1);
}

// 3-phase multi-block exclusive scan. CONTRACT: NB <= 64 (N <= 65536).
__global__ void scan_part1(const int* __restrict__ cnt, int* __restrict__ bsum, int N) {
    __shared__ int ws[4];
    int t = threadIdx.x;                 // 256
    int base = blockIdx.x * 1024;
    int s = 0;
#pragma unroll
    for (int r = 0; r < 4; r++) {
        int i = base + t + 256 * r;
        if (i < N) s += cnt[i];
    }
    for (int d = 1; d < 64; d <<= 1) s += __shfl_xor(s, d);
    if ((t & 63) == 0) ws[t >> 6] = s;
    __syncthreads();
    if (t == 0) bsum[blockIdx.x] = ws[0] + ws[1] + ws[2] + ws[3];
}

__global__ void scan_part2(const int* __restrict__ bsum, int* __restrict__ boff,
                           int* __restrict__ row_off, int NB, int N) {
    int t = threadIdx.x;                 // 64 threads (one wave), NB <= 64
    int v = (t < NB) ? bsum[t] : 0;
    int incl = v;
    for (int d = 1; d < 64; d <<= 1) {
        int n = __shfl_up(incl, d);
        if (t >= d) incl += n;
    }
    if (t < NB) boff[t] = incl - v;
    if (t == 63) row_off[N] = incl;      // grand total
}

__global__ void scan_part3(const int* __restrict__ cnt, const int* __restrict__ boff,
                           int* __restrict__ row_off, int* __restrict__ next_, int N) {
    __shared__ int wsum[4];
    int t = threadIdx.x, lane = t & 63, wid = t >> 6;
    int base = blockIdx.x * 1024;
    int i0 = base + t * 4;
    int e0 = (i0 + 0 < N) ? cnt[i0 + 0] : 0;
    int e1 = (i0 + 1 < N) ? cnt[i0 + 1] : 0;
    int e2 = (i0 + 2 < N) ? cnt[i0 + 2] : 0;
    int e3 = (i0 + 3 < N) ? cnt[i0 + 3] : 0;
    int p0 = e0, p1 = p0 + e1, p2 = p1 + e2, p3 = p2 + e3;
    int incl = p3;
    for (int d = 1; d < 64; d <<= 1) {
        int n = __shfl_up(incl, d);
        if (lane >= d) incl += n;
    }
    int texcl = incl - p3;
    if (lane == 63) wsum[wid] = incl;
    __syncthreads();
    if (t == 0) {
        int a = wsum[0];
        int b = a + wsum[1];
        int c = b + wsum[2];
        wsum[1] = a; wsum[2] = b; wsum[3] = c; wsum[0] = 0;
    }
    __syncthreads();
    int off = boff[blockIdx.x] + wsum[wid] + texcl;
    if (i0 + 0 < N) { row_off[i0 + 0] = off;      next_[i0 + 0] = off; }
    if (i0 + 1 < N) { row_off[i0 + 1] = off + p0; next_[i0 + 1] = off + p0; }
    if (i0 + 2 < N) { row_off[i0 + 2] = off + p1; next_[i0 + 2] = off + p1; }
    if (i0 + 3 < N) { row_off[i0 + 3] = off + p2; next_[i0 + 3] = off + p2; }
}

__global__ void scatter_kernel(const int* __restrict__ src, const int* __restrict__ tgt,
                               int* __restrict__ next_, int* __restrict__ csr_src, int E) {
    int i = blockIdx.x * blockDim.x + threadIdx.x;
    if (i < E) {
        int tg = tgt[i];
        int pos = atomicAdd(&next_[tg], 1);
        csr_src[pos] = src[i];
    }
}

// ---------------- shared GEMM body (R6-measured: 73 TF, VALUBusy 70%) ----------------
// Do NOT reintroduce manual SW-pipelining (R8/R11: register spill, 9.3 GB scratch).
__device__ __forceinline__ void store4(float* p, float4 v) { *(float4*)p = v; }
__device__ __forceinline__ void store4(ushort_t* p, float4 v) {
    ushort4 h;
    h.x = f2bf(v.x); h.y = f2bf(v.y); h.z = f2bf(v.z); h.w = f2bf(v.w);
    *(ushort4*)p = h;
}

template<typename OT>
__device__ __forceinline__ void gemm_body(const float* __restrict__ x, const float* __restrict__ b,
                                          OT* __restrict__ out, int N,
                                          const float* Wl, float* Xl) {
    int t = threadIdx.x;
    int c4 = t & 31;         // cols 4*c4 .. 4*c4+3
    int nl = t >> 5;         // 0..7 ; nodes nl, nl+8, nl+16, nl+24
    float4 bb = *(const float4*)&b[4 * c4];
    for (int nb = blockIdx.x * 32; nb < N; nb += gridDim.x * 32) {
#pragma unroll
        for (int r = 0; r < 4; r++) {
            int idx = t + 256 * r;
            int node = idx >> 5, f4 = idx & 31;
            int gn = nb + node;
            float4 xv = (gn < N) ? *(const float4*)&x[(size_t)gn * F + 4 * f4]
                                 : make_float4(0.f, 0.f, 0.f, 0.f);
            *(float4*)&Xl[node * F + 4 * f4] = xv;
        }
        __syncthreads();
        float4 acc[4];
#pragma unroll
        for (int j = 0; j < 4; j++) acc[j] = bb;
#pragma unroll 2
        for (int f = 0; f < 128; f += 4) {
            float4 w0 = *(const float4*)&Wl[(f + 0) * F + 4 * c4];
            float4 w1 = *(const float4*)&Wl[(f + 1) * F + 4 * c4];
            float4 w2 = *(const float4*)&Wl[(f + 2) * F + 4 * c4];
            float4 w3 = *(const float4*)&Wl[(f + 3) * F + 4 * c4];
#pragma unroll
            for (int j = 0; j < 4; j++) {
                float4 xv = *(const float4*)&Xl[(nl + 8 * j) * F + f];
                acc[j].x += xv.x * w0.x + xv.y * w1.x + xv.z * w2.x + xv.w * w3.x;
                acc[j].y += xv.x * w0.y + xv.y * w1.y + xv.z * w2.y + xv.w * w3.y;
                acc[j].z += xv.x * w0.z + xv.y * w1.z + xv.z * w2.z + xv.w * w3.z;
                acc[j].w += xv.x * w0.w + xv.y * w1.w + xv.z * w2.w + xv.w * w3.w;
            }
        }
#pragma unroll
        for (int j = 0; j < 4; j++) {
            int gn = nb + nl + 8 * j;
            if (gn < N) store4(&out[(size_t)gn * F + 4 * c4], acc[j]);
        }
        __syncthreads();
    }
}

// Q projection (fp32 out). Weight layout w[h][f][d] -> column c = h*32+d.
__global__ __launch_bounds__(256, 2) void proj_q_kernel(
    const float* __restrict__ x, const float* __restrict__ wq, const float* __restrict__ bq,
    float* __restrict__ qo, int N) {
    __shared__ float Wl[128 * 128];
    __shared__ float Xl[32 * 128];
    int t = threadIdx.x;
    int c4 = t & 31, h = c4 >> 3, d4 = c4 & 7;
    const float4* w4 = (const float4*)wq;
#pragma unroll
    for (int r = 0; r < 16; r++) {
        int f = (t >> 5) + 8 * r;
        *(float4*)&Wl[f * F + 4 * c4] = w4[h * 1024 + f * 8 + d4];
    }
    __syncthreads();
    gemm_body<float>(x, bq, qo, N, Wl, Xl);
}

// K/V projections (bf16 out). blockIdx.y: 0 -> k, 1 -> v.
__global__ __launch_bounds__(256, 2) void proj_kv_kernel(
    const float* __restrict__ x,
    const float* __restrict__ wk, const float* __restrict__ bk,
    const float* __restrict__ wv, const float* __restrict__ bv,
    ushort_t* __restrict__ ko, ushort_t* __restrict__ vo, int N) {
    __shared__ float Wl[128 * 128];
    __shared__ float Xl[32 * 128];
    const float* w = blockIdx.y == 0 ? wk : wv;
    const float* b = blockIdx.y == 0 ? bk : bv;
    ushort_t* out = blockIdx.y == 0 ? ko : vo;
    int t = threadIdx.x;
    int c4 = t & 31, h = c4 >> 3, d4 = c4 & 7;
    const float4* w4 = (const float4*)w;
#pragma unroll
    for (int r = 0; r < 16; r++) {
        int f = (t >> 5) + 8 * r;
        *(float4*)&Wl[f * F + 4 * c4] = w4[h * 1024 + f * 8 + d4];
    }
    __syncthreads();
    gemm_body<ushort_t>(x, b, out, N, Wl, Xl);
}

// Final: out = agg @ wo^T + bo ; wo layout [o][f] (transpose gather, L2-resident).
__global__ __launch_bounds__(256, 2) void outproj_kernel(
    const float* __restrict__ aggin, const float* __restrict__ wo,
    const float* __restrict__ bo, float* __restrict__ out, int N) {
    __shared__ float Wl[128 * 128];
    __shared__ float Xl[32 * 128];
    int t = threadIdx.x;
    int c4 = t & 31;
#pragma unroll
    for (int r = 0; r < 16; r++) {
        int f = (t >> 5) + 8 * r;
        float4 wv4;
        wv4.x = wo[(size_t)(4 * c4 + 0) * F + f];
        wv4.y = wo[(size_t)(4 * c4 + 1) * F + f];
        wv4.z = wo[(size_t)(4 * c4 + 2) * F + f];
        wv4.w = wo[(size_t)(4 * c4 + 3) * F + f];
        *(float4*)&Wl[f * F + 4 * c4] = wv4;
    }
    __syncthreads();
    gemm_body<float>(aggin, bo, out, N, Wl, Xl);
}

// ---------------- fused per-node edge attention (bf16 k/v) ----------------
// One wave per target node; online softmax; fp32 aggregate.
// Score phase: lane = slot*4+h4; xor-1/2 completes 32-dim dot; xor-4..32
// reduces chunk stats over slots; p of edge e head h in lane e*4+h; srcn of
// edge e in lane e*4; after reduce, lane h (h<4) holds head h's chunk stats.
// Agg phase (4-way parallel): lane = (g=lane>>4, li=lane&15); round r
// processes edges {r*4+g : g=0..3} concurrently (4 gathers in flight);
// lane covers dims li*8..li*8+7 (head hag=li>>2) via one 16B uint4 bf16 load.
// All lanes sharing li have the same hag -> same den/scale, so the deferred
// cross-group sum (xor 16/32) commutes with per-chunk rescale. g==0 writes.
__global__ __launch_bounds__(256) void edge_attn_kernel(
    const float* __restrict__ q, const ushort_t* __restrict__ kb,
    const ushort_t* __restrict__ vb,
    const int* __restrict__ row_off, const int* __restrict__ csr_src,
    float* __restrict__ agg, int N) {
    int wave = (blockIdx.x * blockDim.x + threadIdx.x) >> 6;
    if (wave >= N) return;          // uniform per wave
    int lane = threadIdx.x & 63;
    int n = wave;
    int h4 = lane & 3;              // score-phase head
    int slot = lane >> 2;           // score-phase edge slot
    int li = lane & 15;             // agg-phase dim group: dims li*8..li*8+7
    int g = lane >> 4;              // agg-phase edge group
    int hag = li >> 2;              // agg-phase head

    float4 qf[8];
#pragma unroll
    for (int i = 0; i < 8; i++)
        qf[i] = *(const float4*)&q[(size_t)n * F + i * 16 + h4 * 4];

    int base = row_off[n];
    int deg = row_off[n + 1] - base;

    float m_sc = -INFINITY;
    float m_ag = -INFINITY;
    float den = 0.f;
    float acc[8] = {0.f, 0.f, 0.f, 0.f, 0.f, 0.f, 0.f, 0.f};

    for (int c0 = 0; c0 < deg; c0 += 16) {
        int mye = c0 + slot;
        int srcn = (mye < deg) ? csr_src[base + mye] : 0;

        float sacc[4] = {0.f, 0.f, 0.f, 0.f};
#pragma unroll
        for (int i = 0; i < 8; i++) {
            ushort4 kk = *(const ushort4*)&kb[(size_t)srcn * F + i * 16 + h4 * 4];
            sacc[i >> 1] += qf[i].x * bf2f(kk.x) + qf[i].y * bf2f(kk.y)
                          + qf[i].z * bf2f(kk.z) + qf[i].w * bf2f(kk.w);
        }
#pragma unroll
        for (int hh = 0; hh < 4; hh++) {
            sacc[hh] += __shfl_xor(sacc[hh], 1);
            sacc[hh] += __shfl_xor(sacc[hh], 2);
        }
        float s = h4 == 0 ? sacc[0] : h4 == 1 ? sacc[1] : h4 == 2 ? sacc[2] : sacc[3];
        if (mye >= deg) s = -INFINITY;

        float cm = s;
        cm = fmaxf(cm, __shfl_xor(cm, 4));
        cm = fmaxf(cm, __shfl_xor(cm, 8));
        cm = fmaxf(cm, __shfl_xor(cm, 16));
        cm = fmaxf(cm, __shfl_xor(cm, 32));

        float nm_sc = fmaxf(m_sc, cm);
        float cm_ag = __shfl(cm, hag);
        float nm_ag = fmaxf(m_ag, cm_ag);

        float p = __expf(s - nm_sc);          // 0 for padded slots
        float psum = p;
        psum += __shfl_xor(psum, 4);
        psum += __shfl_xor(psum, 8);
        psum += __shfl_xor(psum, 16);
        psum += __shfl_xor(psum, 32);

        float scale = __expf(m_ag - nm_ag);   // first chunk: exp(-inf)=0, safe
        den = den * scale + __shfl(psum, hag);
#pragma unroll
        for (int d = 0; d < 8; d++) acc[d] *= scale;

        // 4-way parallel aggregation: round r, group g handles edge r*4+g
#pragma unroll
        for (int r = 0; r < 4; r++) {
            int e = (r << 2) | g;
            float pj = __shfl(p, (e << 2) | hag);   // 0 for padded edges
            int sj = __shfl(srcn, e << 2);
            uint4 vv = *(const uint4*)&vb[(size_t)sj * F + li * 8];
            acc[0] += pj * bf2f((ushort_t)(vv.x & 0xFFFFu));
            acc[1] += pj * bf2f((ushort_t)(vv.x >> 16));
            acc[2] += pj * bf2f((ushort_t)(vv.y & 0xFFFFu));
            acc[3] += pj * bf2f((ushort_t)(vv.y >> 16));
            acc[4] += pj * bf2f((ushort_t)(vv.z & 0xFFFFu));
            acc[5] += pj * bf2f((ushort_t)(vv.z >> 16));
            acc[6] += pj * bf2f((ushort_t)(vv.w & 0xFFFFu));
            acc[7] += pj * bf2f((ushort_t)(vv.w >> 16));
        }
        m_sc = nm_sc;
        m_ag = nm_ag;
    }
    // sum edge groups (lanes li, li+16, li+32, li+48 hold disjoint edge subsets)
#pragma unroll
    for (int d = 0; d < 8; d++) {
        acc[d] += __shfl_xor(acc[d], 16);
        acc[d] += __shfl_xor(acc[d], 32);
    }
    float inv = (den > 0.f) ? 1.f / den : 0.f;   // deg==0 -> zeros (ref: out=bo)
    if (g == 0) {
        float4 o0 = make_float4(acc[0] * inv, acc[1] * inv, acc[2] * inv, acc[3] * inv);
        float4 o1 = make_float4(acc[4] * inv, acc[5] * inv, acc[6] * inv, acc[7] * inv);
        *(float4*)&agg[(size_t)n * F + li * 8] = o0;
        *(float4*)&agg[(size_t)n * F + li * 8 + 4] = o1;
    }
}

// ---------------- launch ----------------
extern "C" void kernel_launch(void* const* d_in, const int* in_sizes, int n_in,
                              void* d_out, int out_size, void* d_ws, size_t ws_size,
                              hipStream_t stream) {
    const float* x  = (const float*)d_in[0];
    const int*   ei = (const int*)d_in[1];
    const float* wq = (const float*)d_in[2];
    const float* bq = (const float*)d_in[3];
    const float* wk = (const float*)d_in[4];
    const float* bk = (const float*)d_in[5];
    const float* wv = (const float*)d_in[6];
    const float* bv = (const float*)d_in[7];
    const float* wo = (const float*)d_in[8];
    const float* bo = (const float*)d_in[9];
    float* out = (float*)d_out;

    int N = in_sizes[0] / F;
    int E = in_sizes[1] / 2;
    const int* srcs = ei;
    const int* tgts = ei + E;

    size_t need = (size_t)N * F * 4 * 2        // q, agg (fp32)
                + (size_t)N * F * 2 * 2        // k, v (bf16)
                + (size_t)(N + 1) * 4          // row_off
                + (size_t)N * 4 * 2            // next_, cnt
                + (size_t)E * 4                // csr_src
                + 128 * 4;                     // bsum, boff
    if (ws_size < need) return;

    char* wsp = (char*)d_ws;
    float* q       = (float*)wsp;    wsp += (size_t)N * F * 4;
    float* agg     = (float*)wsp;    wsp += (size_t)N * F * 4;
    ushort_t* kb   = (ushort_t*)wsp; wsp += (size_t)N * F * 2;
    ushort_t* vb   = (ushort_t*)wsp; wsp += (size_t)N * F * 2;
    int* row_off = (int*)wsp; wsp += (size_t)(N + 1) * 4;
    int* next_   = (int*)wsp; wsp += (size_t)N * 4;
    int* cnt     = (int*)wsp; wsp += (size_t)N * 4;
    int* csr_src = (int*)wsp; wsp += (size_t)E * 4;
    int* bsum    = (int*)wsp; wsp += 64 * 4;
    int* boff    = (int*)wsp; wsp += 64 * 4;

    int NB = (N + 1023) >> 10;   // 49 for N=50000; scan_part2 requires NB<=64

    hipMemsetAsync(cnt, 0, (size_t)N * 4, stream);
    hist_kernel<<<(E + 255) / 256, 256, 0, stream>>>(tgts, cnt, E);
    scan_part1<<<NB, 256, 0, stream>>>(cnt, bsum, N);
    scan_part2<<<1, 64, 0, stream>>>(bsum, boff, row_off, NB, N);
    scan_part3<<<NB, 256, 0, stream>>>(cnt, boff, row_off, next_, N);
    scatter_kernel<<<(E + 255) / 256, 256, 0, stream>>>(srcs, tgts, next_, csr_src, E);
    proj_q_kernel<<<512, 256, 0, stream>>>(x, wq, bq, q, N);
    proj_kv_kernel<<<dim3(512, 2), 256, 0, stream>>>(x, wk, bk, wv, bv, kb, vb, N);
    edge_attn_kernel<<<(N + 3) / 4, 256, 0, stream>>>(q, kb, vb, row_off, csr_src, agg, N);
    outproj_kernel<<<512, 256, 0, stream>>>(agg, wo, bo, out, N);
}